// Round 2
// baseline (984.909 us; speedup 1.0000x reference)
//
#include <hip/hip_runtime.h>
#include <math.h>

// Problem constants (Physics_Attention_Irregular_Mesh)
#define BQ   4
#define NTOK 16384
#define DIMM 256
#define HH   8
#define DDIM 64
#define SSL  64
#define INNERD 512
#define BN_TOK (BQ*NTOK)   // 65536

// bf16 <-> f32 helpers (RNE)
__device__ inline float bf2f(unsigned short u) {
    union { float f; unsigned int i; } v; v.i = ((unsigned int)u) << 16; return v.f;
}
__device__ inline unsigned short f2bf(float f) {
    union { float f; unsigned int i; } v; v.f = f;
    unsigned int r = v.i + 0x7FFFu + ((v.i >> 16) & 1u);
    return (unsigned short)(r >> 16);
}

// ---------------------------------------------------------------------------
// K0: build merged weights
//   Wcat rows 0..511    = Wfx (fx projection),          bcat = bfx
//   Wcat rows 512..1023 = Wslice @ Wx_h (logits proj),  bcat = Wslice@bx_h + bslice
// ---------------------------------------------------------------------------
__global__ void k_prep(const float* __restrict__ Wx, const float* __restrict__ bx,
                       const float* __restrict__ Wfx, const float* __restrict__ bfx,
                       const float* __restrict__ Wslice, const float* __restrict__ bslice,
                       float* __restrict__ Wcat, float* __restrict__ bcat)
{
    int row = blockIdx.x;   // 0..1023
    int t = threadIdx.x;    // 64 threads
    if (row < 512) {
        for (int c = t; c < 256; c += 64) Wcat[row*256 + c] = Wfx[row*256 + c];
        if (t == 0) bcat[row] = bfx[row];
    } else {
        int r = row - 512, h = r >> 6, s = r & 63;
        for (int c = t; c < 256; c += 64) {
            float acc = 0.f;
            for (int d = 0; d < 64; ++d)
                acc += Wslice[s*64 + d] * Wx[(h*64 + d)*256 + c];
            Wcat[row*256 + c] = acc;
        }
        if (t == 0) {
            float acc = bslice[s];
            for (int d = 0; d < 64; ++d) acc += Wslice[s*64 + d] * bx[h*64 + d];
            bcat[row] = acc;
        }
    }
}

// ---------------------------------------------------------------------------
// K1a: fused projection GEMM. C[65536 x 1024] = x[65536 x 256] @ Wcat^T + bcat
//   cols 0..511  -> fx (bf16)     cols 512..1023 -> logits wl (bf16)
// 128x128 tile, BK=16, 256 threads, 8x8 microtile.
// ---------------------------------------------------------------------------
#define TBK 16
__global__ __launch_bounds__(256) void k_gemm1(
    const float* __restrict__ A, const float* __restrict__ Bm,
    const float* __restrict__ bias,
    unsigned short* __restrict__ fx, unsigned short* __restrict__ wl)
{
    __shared__ float As[TBK][128+4];
    __shared__ float Bs[TBK][128+4];
    int bid = blockIdx.x;                 // 4096 blocks
    int group = bid >> 6;
    int within = bid & 63;
    int rt = group*8 + (within >> 3);     // 0..511
    int ct = within & 7;                  // 0..7
    int m0 = rt * 128, n0 = ct * 128;
    int tid = threadIdx.x;
    int tx = tid & 15, ty = tid >> 4;

    float acc[8][8];
#pragma unroll
    for (int i = 0; i < 8; i++)
#pragma unroll
        for (int j = 0; j < 8; j++) acc[i][j] = 0.f;

    for (int k0 = 0; k0 < 256; k0 += TBK) {
#pragma unroll
        for (int i = 0; i < 2; i++) {
            int flat = tid + i*256;           // 0..511
            int row = flat >> 2;
            int kq  = (flat & 3) * 4;
            float4 va = *(const float4*)(A + (size_t)(m0+row)*256 + k0 + kq);
            As[kq+0][row]=va.x; As[kq+1][row]=va.y; As[kq+2][row]=va.z; As[kq+3][row]=va.w;
            float4 vb = *(const float4*)(Bm + (size_t)(n0+row)*256 + k0 + kq);
            Bs[kq+0][row]=vb.x; Bs[kq+1][row]=vb.y; Bs[kq+2][row]=vb.z; Bs[kq+3][row]=vb.w;
        }
        __syncthreads();
#pragma unroll
        for (int k = 0; k < TBK; k++) {
            float a0[8], b0[8];
            *(float4*)&a0[0] = *(const float4*)&As[k][ty*8];
            *(float4*)&a0[4] = *(const float4*)&As[k][ty*8+4];
            *(float4*)&b0[0] = *(const float4*)&Bs[k][tx*8];
            *(float4*)&b0[4] = *(const float4*)&Bs[k][tx*8+4];
#pragma unroll
            for (int i = 0; i < 8; i++)
#pragma unroll
                for (int j = 0; j < 8; j++) acc[i][j] += a0[i]*b0[j];
        }
        __syncthreads();
    }
#pragma unroll
    for (int i = 0; i < 8; i++) {
        int m = m0 + ty*8 + i;
        int nb = n0 + tx*8;               // 8 contiguous cols, never straddles 512
        unsigned short tmp[8];
#pragma unroll
        for (int j = 0; j < 8; j++) tmp[j] = f2bf(acc[i][j] + bias[nb + j]);
        unsigned short* dst; size_t off;
        if (nb < 512) { dst = fx; off = (size_t)m*512 + nb; }
        else          { dst = wl; off = (size_t)m*512 + nb - 512; }
        *(ushort4*)(dst + off)     = make_ushort4(tmp[0], tmp[1], tmp[2], tmp[3]);
        *(ushort4*)(dst + off + 4) = make_ushort4(tmp[4], tmp[5], tmp[6], tmp[7]);
    }
}

// ---------------------------------------------------------------------------
// K1b: softmax over S=64 per (token, head); logits /= max(temp,1e-4) first.
// One wave per row, 8 rows per wave. bf16 in/out.
// ---------------------------------------------------------------------------
__global__ void k_softmax(unsigned short* __restrict__ wl, const float* __restrict__ temperature)
{
    long long wave = (long long)((blockIdx.x * blockDim.x + threadIdx.x) >> 6);
    int lane = threadIdx.x & 63;
    for (int r = 0; r < 8; ++r) {
        long long row = wave * 8 + r;         // 0 .. 65536*8-1
        int h = (int)(row & 7);
        float t = fmaxf(temperature[h], 1e-4f);
        float v = bf2f(wl[row*64 + lane]) / t;
        float mx = v;
        for (int off = 32; off; off >>= 1) mx = fmaxf(mx, __shfl_xor(mx, off));
        float e = expf(v - mx);
        float sm = e;
        for (int off = 32; off; off >>= 1) sm += __shfl_xor(sm, off);
        wl[row*64 + lane] = f2bf(e / sm);
    }
}

// ---------------------------------------------------------------------------
// K2: tok_acc[b,h,s,d] += sum_n w[b,n,h,s]*fx[b,n,h,d]; norm[b,h,s] += sum_n w
// grid (chunk=16, h=8, b=4); chunk = 1024 tokens, staged 64 at a time.
// ---------------------------------------------------------------------------
__global__ __launch_bounds__(256) void k_tok(
    const unsigned short* __restrict__ wbuf, const unsigned short* __restrict__ fx,
    float* __restrict__ tok_acc, float* __restrict__ norm_acc)
{
    __shared__ float Wsm[64][68];
    __shared__ float Fsm[64][68];
    int chunk = blockIdx.x, h = blockIdx.y, b = blockIdx.z;
    int n0 = chunk * 1024;
    int tid = threadIdx.x;
    int tx = tid & 15, ty = tid >> 4;
    float acc[4][4] = {{0.f}};
    float nsum = 0.f;

    for (int kk = 0; kk < 1024; kk += 64) {
#pragma unroll
        for (int i = 0; i < 4; i++) {
            int flat = tid + i*256;         // 0..1023
            int tr = flat >> 4;             // 0..63
            int c4 = (flat & 15) * 4;
            size_t base = ((size_t)(b*NTOK + n0 + kk + tr))*512 + h*64 + c4;
            ushort4 wv = *(const ushort4*)(wbuf + base);
            Wsm[tr][c4+0]=bf2f(wv.x); Wsm[tr][c4+1]=bf2f(wv.y);
            Wsm[tr][c4+2]=bf2f(wv.z); Wsm[tr][c4+3]=bf2f(wv.w);
            ushort4 fv = *(const ushort4*)(fx + base);
            Fsm[tr][c4+0]=bf2f(fv.x); Fsm[tr][c4+1]=bf2f(fv.y);
            Fsm[tr][c4+2]=bf2f(fv.z); Fsm[tr][c4+3]=bf2f(fv.w);
        }
        __syncthreads();
#pragma unroll 8
        for (int k = 0; k < 64; k++) {
            float av[4], bv[4];
            *(float4*)av = *(const float4*)&Wsm[k][ty*4];
            *(float4*)bv = *(const float4*)&Fsm[k][tx*4];
#pragma unroll
            for (int i = 0; i < 4; i++)
#pragma unroll
                for (int j = 0; j < 4; j++) acc[i][j] += av[i]*bv[j];
        }
        if (tid < 64) {
            float s = 0.f;
            for (int k = 0; k < 64; k++) s += Wsm[k][tid];
            nsum += s;
        }
        __syncthreads();
    }
    int bh = b*8 + h;
#pragma unroll
    for (int i = 0; i < 4; i++) {
        int s = ty*4 + i;
#pragma unroll
        for (int j = 0; j < 4; j++) {
            int d = tx*4 + j;
            atomicAdd(&tok_acc[((size_t)bh*64 + s)*64 + d], acc[i][j]);
        }
    }
    if (tid < 64) atomicAdd(&norm_acc[bh*64 + tid], nsum);
}

// K3a: tok /= (norm + 1e-5), in place
__global__ void k_fintok(float* __restrict__ tok, const float* __restrict__ norm)
{
    int bh = blockIdx.x, tid = threadIdx.x;
    for (int idx = tid; idx < 4096; idx += 256) {
        int s = idx >> 6;
        tok[(size_t)bh*4096 + idx] /= (norm[bh*64 + s] + 1e-5f);
    }
}

// K3b: per b: kv = mean_h tok; k = kv@Wk^T (row-normalized -> kn); v = kv@Wv^T
__global__ __launch_bounds__(256) void k_kv(
    const float* __restrict__ tok, const float* __restrict__ Wk, const float* __restrict__ Wv,
    float* __restrict__ kn_out, float* __restrict__ v_out)
{
    __shared__ float KV[64][65];
    __shared__ float TMP[64][65];
    __shared__ float rn[64];
    int b = blockIdx.x, tid = threadIdx.x;
    for (int idx = tid; idx < 4096; idx += 256) {
        float s = 0.f;
        for (int h = 0; h < 8; ++h) s += tok[((size_t)(b*8 + h))*4096 + idx];
        KV[idx >> 6][idx & 63] = s * 0.125f;
    }
    __syncthreads();
    for (int idx = tid; idx < 4096; idx += 256) {
        int s = idx >> 6, d = idx & 63;
        float a = 0.f;
        for (int e = 0; e < 64; ++e) a += KV[s][e] * Wk[d*64 + e];
        TMP[s][d] = a;
    }
    __syncthreads();
    if (tid < 64) {
        float a = 0.f;
        for (int d = 0; d < 64; ++d) { float x = TMP[tid][d]; a += x*x; }
        rn[tid] = fmaxf(sqrtf(a), 1e-12f);
    }
    __syncthreads();
    for (int idx = tid; idx < 4096; idx += 256) {
        int s = idx >> 6, d = idx & 63;
        kn_out[(size_t)b*4096 + idx] = TMP[s][d] / rn[s];
    }
    for (int idx = tid; idx < 4096; idx += 256) {
        int s = idx >> 6, d = idx & 63;
        float a = 0.f;
        for (int e = 0; e < 64; ++e) a += KV[s][e] * Wv[d*64 + e];
        v_out[(size_t)b*4096 + idx] = a;
    }
}

// K3c: per (b,h): q = tok@Wq^T, cosine logits vs kn, softmax, @v, + srs*tok
__global__ __launch_bounds__(256) void k_attn(
    const float* __restrict__ tok, const float* __restrict__ Wq,
    const float* __restrict__ kn, const float* __restrict__ vbuf,
    const float* __restrict__ attn_scale, const float* __restrict__ srs,
    float* __restrict__ out_tok)
{
    __shared__ float Q[64][65];
    __shared__ float KN[64][65];
    __shared__ float L[64][65];
    __shared__ float rn[64];
    int h = blockIdx.x & 7, b = blockIdx.x >> 3;
    int bh = b*8 + h;
    int tid = threadIdx.x;
    for (int idx = tid; idx < 4096; idx += 256)
        KN[idx >> 6][idx & 63] = kn[(size_t)b*4096 + idx];
    __syncthreads();
    for (int idx = tid; idx < 4096; idx += 256) {
        int g = idx >> 6, d = idx & 63;
        float a = 0.f;
        for (int e = 0; e < 64; ++e) a += tok[(size_t)bh*4096 + g*64 + e] * Wq[d*64 + e];
        Q[g][d] = a;
    }
    __syncthreads();
    if (tid < 64) {
        float a = 0.f;
        for (int d = 0; d < 64; ++d) { float x = Q[tid][d]; a += x*x; }
        rn[tid] = fmaxf(sqrtf(a), 1e-12f);
    }
    __syncthreads();
    float scale = attn_scale[h];
    for (int idx = tid; idx < 4096; idx += 256) {
        int g = idx >> 6, s = idx & 63;
        float a = 0.f;
        for (int e = 0; e < 64; ++e) a += Q[g][e] * KN[s][e];
        L[g][s] = a / rn[g] * scale;
    }
    __syncthreads();
    if (tid < 64) {
        float mx = -1e30f;
        for (int s = 0; s < 64; ++s) mx = fmaxf(mx, L[tid][s]);
        float sm = 0.f;
        for (int s = 0; s < 64; ++s) { float e = expf(L[tid][s]-mx); L[tid][s] = e; sm += e; }
        float inv = 1.f/sm;
        for (int s = 0; s < 64; ++s) L[tid][s] *= inv;
    }
    __syncthreads();
    float srsv = srs[0];
    for (int idx = tid; idx < 4096; idx += 256) {
        int g = idx >> 6, d = idx & 63;
        float a = 0.f;
        for (int s = 0; s < 64; ++s) a += L[g][s] * vbuf[(size_t)b*4096 + s*64 + d];
        out_tok[(size_t)bh*4096 + idx] = a + srsv * tok[(size_t)bh*4096 + idx];
    }
}

// K3d: MT[b][j][h*64+s] = sum_d out_tok[b,h,s,d] * Wout[j, h*64+d]
// grid (jt=4, h=8, b=4); 64x64 output tile, K=64.
__global__ __launch_bounds__(256) void k_mt(
    const float* __restrict__ out_tok, const float* __restrict__ Wout,
    float* __restrict__ MT)
{
    __shared__ float Wt[64][68];   // [d][j]
    __shared__ float Ot[64][68];   // [d][s]
    int jt = blockIdx.x, h = blockIdx.y, b = blockIdx.z;
    int j0 = jt * 64;
    int tid = threadIdx.x;
    int tx = tid & 15, ty = tid >> 4;
#pragma unroll
    for (int i = 0; i < 4; i++) {
        int flat = tid + i*256;
        int r = flat >> 4;             // row (j or s)
        int c4 = (flat & 15) * 4;      // d
        float4 wv = *(const float4*)(Wout + (size_t)(j0+r)*512 + h*64 + c4);
        Wt[c4+0][r]=wv.x; Wt[c4+1][r]=wv.y; Wt[c4+2][r]=wv.z; Wt[c4+3][r]=wv.w;
        float4 ov = *(const float4*)(out_tok + ((size_t)(b*8+h)*64 + r)*64 + c4);
        Ot[c4+0][r]=ov.x; Ot[c4+1][r]=ov.y; Ot[c4+2][r]=ov.z; Ot[c4+3][r]=ov.w;
    }
    __syncthreads();
    float acc[4][4] = {{0.f}};
#pragma unroll 8
    for (int d = 0; d < 64; ++d) {
        float av[4], bv[4];
        *(float4*)av = *(const float4*)&Wt[d][ty*4];
        *(float4*)bv = *(const float4*)&Ot[d][tx*4];
#pragma unroll
        for (int i = 0; i < 4; i++)
#pragma unroll
            for (int j = 0; j < 4; j++) acc[i][j] += av[i]*bv[j];
    }
#pragma unroll
    for (int i = 0; i < 4; i++) {
        int j = j0 + ty*4 + i;
#pragma unroll
        for (int jj = 0; jj < 4; jj++) {
            int s = tx*4 + jj;
            MT[((size_t)(b*256) + j)*512 + h*64 + s] = acc[i][jj];
        }
    }
}

// ---------------------------------------------------------------------------
// K5: out[65536 x 256] = wbuf[65536 x 512](bf16) @ MT[b]^T + bout
// ---------------------------------------------------------------------------
__global__ __launch_bounds__(256) void k_gemm2(
    const unsigned short* __restrict__ A, const float* __restrict__ Ball,
    const float* __restrict__ bias, float* __restrict__ C)
{
    __shared__ float As[TBK][128+4];
    __shared__ float Bs[TBK][128+4];
    int bid = blockIdx.x;           // 1024
    int rt = bid >> 1, ct = bid & 1;
    int m0 = rt * 128, n0 = ct * 128;
    int b = m0 / NTOK;
    const float* Bm = Ball + (size_t)b * 256 * 512;
    int tid = threadIdx.x;
    int tx = tid & 15, ty = tid >> 4;

    float acc[8][8];
#pragma unroll
    for (int i = 0; i < 8; i++)
#pragma unroll
        for (int j = 0; j < 8; j++) acc[i][j] = 0.f;

    for (int k0 = 0; k0 < 512; k0 += TBK) {
#pragma unroll
        for (int i = 0; i < 2; i++) {
            int flat = tid + i*256;
            int row = flat >> 2;
            int kq  = (flat & 3) * 4;
            ushort4 va = *(const ushort4*)(A + (size_t)(m0+row)*512 + k0 + kq);
            As[kq+0][row]=bf2f(va.x); As[kq+1][row]=bf2f(va.y);
            As[kq+2][row]=bf2f(va.z); As[kq+3][row]=bf2f(va.w);
            float4 vb = *(const float4*)(Bm + (size_t)(n0+row)*512 + k0 + kq);
            Bs[kq+0][row]=vb.x; Bs[kq+1][row]=vb.y; Bs[kq+2][row]=vb.z; Bs[kq+3][row]=vb.w;
        }
        __syncthreads();
#pragma unroll
        for (int k = 0; k < TBK; k++) {
            float a0[8], b0[8];
            *(float4*)&a0[0] = *(const float4*)&As[k][ty*8];
            *(float4*)&a0[4] = *(const float4*)&As[k][ty*8+4];
            *(float4*)&b0[0] = *(const float4*)&Bs[k][tx*8];
            *(float4*)&b0[4] = *(const float4*)&Bs[k][tx*8+4];
#pragma unroll
            for (int i = 0; i < 8; i++)
#pragma unroll
                for (int j = 0; j < 8; j++) acc[i][j] += a0[i]*b0[j];
        }
        __syncthreads();
    }
#pragma unroll
    for (int i = 0; i < 8; i++) {
        int m = m0 + ty*8 + i;
#pragma unroll
        for (int j = 0; j < 8; j++) {
            int nn = n0 + tx*8 + j;
            C[(size_t)m*256 + nn] = acc[i][j] + bias[nn];
        }
    }
}

// ---------------------------------------------------------------------------
extern "C" void kernel_launch(void* const* d_in, const int* in_sizes, int n_in,
                              void* d_out, int out_size, void* d_ws, size_t ws_size,
                              hipStream_t stream)
{
    const float* x      = (const float*)d_in[0];
    const float* Wx     = (const float*)d_in[1];
    const float* bx     = (const float*)d_in[2];
    const float* Wfx    = (const float*)d_in[3];
    const float* bfx    = (const float*)d_in[4];
    const float* Wslice = (const float*)d_in[5];
    const float* bslice = (const float*)d_in[6];
    const float* temperature = (const float*)d_in[7];
    const float* Wq     = (const float*)d_in[8];
    const float* Wk     = (const float*)d_in[9];
    const float* Wv     = (const float*)d_in[10];
    const float* attn_scale = (const float*)d_in[11];
    const float* srs    = (const float*)d_in[12];
    const float* Wout   = (const float*)d_in[13];
    const float* bout   = (const float*)d_in[14];
    float* out = (float*)d_out;
    float* ws  = (float*)d_ws;

    // workspace layout (float offsets) — total ~68.2 MiB, well under budget
    float* tok  = ws + 0;          // 4*8*64*64            = 131072
    float* norm = ws + 131072;     // 4*8*64               = 2048
    float* Wcat = ws + 133120;     // 1024*256             = 262144
    float* bcat = ws + 395264;     // 1024
    float* kn   = ws + 396288;     // 4*64*64              = 16384
    float* vb   = ws + 412672;     // 16384
    float* ot   = ws + 429056;     // 131072
    float* MT   = ws + 560128;     // 4*256*512            = 524288
    unsigned short* wbuf = (unsigned short*)(ws + 1084416); // 65536*512 bf16 = 64 MiB
    // fx (bf16, 64 MiB) lives in d_out scratch; consumed by k_tok before k_gemm2 overwrites
    unsigned short* fx = (unsigned short*)d_out;

    hipMemsetAsync(tok, 0, 133120 * sizeof(float), stream);  // tok_acc + norm
    k_prep<<<1024, 64, 0, stream>>>(Wx, bx, Wfx, bfx, Wslice, bslice, Wcat, bcat);
    k_gemm1<<<4096, 256, 0, stream>>>(x, Wcat, bcat, fx, wbuf);
    k_softmax<<<16384, 256, 0, stream>>>(wbuf, temperature);
    k_tok<<<dim3(16, 8, 4), 256, 0, stream>>>(wbuf, fx, tok, norm);
    k_fintok<<<32, 256, 0, stream>>>(tok, norm);
    k_kv<<<4, 256, 0, stream>>>(tok, Wk, Wv, kn, vb);
    k_attn<<<32, 256, 0, stream>>>(tok, Wq, kn, vb, attn_scale, srs, ot);
    k_mt<<<dim3(4, 8, 4), 256, 0, stream>>>(ot, Wout, MT);
    k_gemm2<<<1024, 256, 0, stream>>>(wbuf, MT, bout, out);
}

// Round 3
// 549.055 us; speedup vs baseline: 1.7938x; 1.7938x over previous
//
#include <hip/hip_runtime.h>
#include <math.h>

// Problem constants (Physics_Attention_Irregular_Mesh)
#define BQ   4
#define NTOK 16384
#define DIMM 256
#define HH   8
#define DDIM 64
#define SSL  64
#define INNERD 512
#define BN_TOK (BQ*NTOK)   // 65536

typedef __attribute__((ext_vector_type(8))) short short8;   // 8 bf16 (4 VGPRs)
typedef __attribute__((ext_vector_type(4))) float f32x4;    // 4 fp32 acc

// bf16 <-> f32 helpers (RNE)
__device__ inline float bf2f(unsigned short u) {
    union { float f; unsigned int i; } v; v.i = ((unsigned int)u) << 16; return v.f;
}
__device__ inline unsigned short f2bf(float f) {
    union { float f; unsigned int i; } v; v.f = f;
    unsigned int r = v.i + 0x7FFFu + ((v.i >> 16) & 1u);
    return (unsigned short)(r >> 16);
}

// async global->LDS, 16 B per lane (wave-uniform LDS base + lane*16)
__device__ __forceinline__ void gl_lds16(const void* g, void* l) {
    __builtin_amdgcn_global_load_lds(
        (const __attribute__((address_space(1))) unsigned int*)g,
        (__attribute__((address_space(3))) unsigned int*)l, 16, 0, 0);
}

// ---------------------------------------------------------------------------
// K0: merged weights (bf16 out).
//   Wcatb rows 0..511    = Wfx,                 bcat = bfx
//   Wcatb rows 512..1023 = Wslice @ Wx_h,       bcat = Wslice@bx_h + bslice
// ---------------------------------------------------------------------------
__global__ void k_prep(const float* __restrict__ Wx, const float* __restrict__ bx,
                       const float* __restrict__ Wfx, const float* __restrict__ bfx,
                       const float* __restrict__ Wslice, const float* __restrict__ bslice,
                       unsigned short* __restrict__ Wcatb, float* __restrict__ bcat)
{
    int row = blockIdx.x;   // 0..1023
    int t = threadIdx.x;    // 64
    if (row < 512) {
        for (int c = t; c < 256; c += 64) Wcatb[row*256 + c] = f2bf(Wfx[row*256 + c]);
        if (t == 0) bcat[row] = bfx[row];
    } else {
        int r = row - 512, h = r >> 6, s = r & 63;
        for (int c = t; c < 256; c += 64) {
            float acc = 0.f;
            for (int d = 0; d < 64; ++d)
                acc += Wslice[s*64 + d] * Wx[(h*64 + d)*256 + c];
            Wcatb[row*256 + c] = f2bf(acc);
        }
        if (t == 0) {
            float acc = bslice[s];
            for (int d = 0; d < 64; ++d) acc += Wslice[s*64 + d] * bx[h*64 + d];
            bcat[row] = acc;
        }
    }
}

// x (fp32) -> xb (bf16), 8 elems/thread
__global__ void k_xcast(const float* __restrict__ x, unsigned short* __restrict__ xb)
{
    size_t i = ((size_t)blockIdx.x*256 + threadIdx.x)*8;
    float4 a = *(const float4*)(x + i);
    float4 b = *(const float4*)(x + i + 4);
    *(ushort4*)(xb + i)     = make_ushort4(f2bf(a.x), f2bf(a.y), f2bf(a.z), f2bf(a.w));
    *(ushort4*)(xb + i + 4) = make_ushort4(f2bf(b.x), f2bf(b.y), f2bf(b.z), f2bf(b.w));
}

// ---------------------------------------------------------------------------
// K1a: MFMA GEMM. C[65536 x 1024] = xb @ Wcatb^T + bcat -> bf16 fx / wl
// 128x128 tile, 4 waves (2x2), each wave 4x4 frags 16x16x32, BK=32.
// ---------------------------------------------------------------------------
__global__ __launch_bounds__(256) void k_gemm1(
    const unsigned short* __restrict__ Xb, const unsigned short* __restrict__ Wb,
    const float* __restrict__ bias,
    unsigned short* __restrict__ fx, unsigned short* __restrict__ wl)
{
    __shared__ unsigned short As[128*32];
    __shared__ unsigned short Bs[128*32];
    int bid = blockIdx.x;             // 4096
    int rt = bid >> 3, ct = bid & 7;  // consecutive blocks share rt (A-tile L2 reuse)
    int m0 = rt*128, n0 = ct*128;
    int tid = threadIdx.x;
    int lane = tid & 63, w = tid >> 6;
    int wr = w >> 1, wc = w & 1;
    int lr = lane & 15, lq = lane >> 4;

    f32x4 acc[4][4];
#pragma unroll
    for (int i = 0; i < 4; i++)
#pragma unroll
        for (int j = 0; j < 4; j++) acc[i][j] = (f32x4)(0.f);

    int r0 = tid >> 2, kq0 = (tid & 3) * 8;   // staging slot

    for (int k0 = 0; k0 < 256; k0 += 32) {
        __syncthreads();
        gl_lds16(Xb + (size_t)(m0 + r0)*256 + k0 + kq0,      &As[(size_t)tid*8]);
        gl_lds16(Xb + (size_t)(m0 + 64 + r0)*256 + k0 + kq0, &As[(size_t)(tid+256)*8]);
        gl_lds16(Wb + (size_t)(n0 + r0)*256 + k0 + kq0,      &Bs[(size_t)tid*8]);
        gl_lds16(Wb + (size_t)(n0 + 64 + r0)*256 + k0 + kq0, &Bs[(size_t)(tid+256)*8]);
        __syncthreads();
        short8 af[4], bf[4];
#pragma unroll
        for (int i = 0; i < 4; i++) {
            af[i] = *(const short8*)&As[(wr*64 + i*16 + lr)*32 + lq*8];
            bf[i] = *(const short8*)&Bs[(wc*64 + i*16 + lr)*32 + lq*8];
        }
#pragma unroll
        for (int i = 0; i < 4; i++)
#pragma unroll
            for (int j = 0; j < 4; j++)
                acc[i][j] = __builtin_amdgcn_mfma_f32_16x16x32_bf16(af[i], bf[j], acc[i][j], 0, 0, 0);
    }

    bool isfx = (n0 < 512);
    unsigned short* dst = isfx ? fx : wl;
    int nloc0 = n0 - (isfx ? 0 : 512) + wc*64;
#pragma unroll
    for (int j = 0; j < 4; j++) {
        int n = nloc0 + j*16 + lr;
        float bv = bias[n0 + wc*64 + j*16 + lr];
#pragma unroll
        for (int i = 0; i < 4; i++) {
            int mrow = m0 + wr*64 + i*16 + lq*4;
#pragma unroll
            for (int r = 0; r < 4; r++)
                dst[(size_t)(mrow + r)*512 + n] = f2bf(acc[i][j][r] + bv);
        }
    }
}

// ---------------------------------------------------------------------------
// K1b: softmax over S=64 per (token, head); logits /= max(temp,1e-4).
// ---------------------------------------------------------------------------
__global__ void k_softmax(unsigned short* __restrict__ wl, const float* __restrict__ temperature)
{
    long long wave = (long long)((blockIdx.x * blockDim.x + threadIdx.x) >> 6);
    int lane = threadIdx.x & 63;
    for (int r = 0; r < 8; ++r) {
        long long row = wave * 8 + r;
        int h = (int)(row & 7);
        float t = fmaxf(temperature[h], 1e-4f);
        float v = bf2f(wl[row*64 + lane]) / t;
        float mx = v;
        for (int off = 32; off; off >>= 1) mx = fmaxf(mx, __shfl_xor(mx, off));
        float e = expf(v - mx);
        float sm = e;
        for (int off = 32; off; off >>= 1) sm += __shfl_xor(sm, off);
        wl[row*64 + lane] = f2bf(e / sm);
    }
}

// ---------------------------------------------------------------------------
// K2: tok_acc[b,h,s,d] += sum_n w[b,n,h,s]*fx[b,n,h,d]; norm += sum_n w
// ---------------------------------------------------------------------------
__global__ __launch_bounds__(256) void k_tok(
    const unsigned short* __restrict__ wbuf, const unsigned short* __restrict__ fx,
    float* __restrict__ tok_acc, float* __restrict__ norm_acc)
{
    __shared__ float Wsm[64][68];
    __shared__ float Fsm[64][68];
    int chunk = blockIdx.x, h = blockIdx.y, b = blockIdx.z;
    int n0 = chunk * 1024;
    int tid = threadIdx.x;
    int tx = tid & 15, ty = tid >> 4;
    float acc[4][4] = {{0.f}};
    float nsum = 0.f;

    for (int kk = 0; kk < 1024; kk += 64) {
#pragma unroll
        for (int i = 0; i < 4; i++) {
            int flat = tid + i*256;
            int tr = flat >> 4;
            int c4 = (flat & 15) * 4;
            size_t base = ((size_t)(b*NTOK + n0 + kk + tr))*512 + h*64 + c4;
            ushort4 wv = *(const ushort4*)(wbuf + base);
            Wsm[tr][c4+0]=bf2f(wv.x); Wsm[tr][c4+1]=bf2f(wv.y);
            Wsm[tr][c4+2]=bf2f(wv.z); Wsm[tr][c4+3]=bf2f(wv.w);
            ushort4 fv = *(const ushort4*)(fx + base);
            Fsm[tr][c4+0]=bf2f(fv.x); Fsm[tr][c4+1]=bf2f(fv.y);
            Fsm[tr][c4+2]=bf2f(fv.z); Fsm[tr][c4+3]=bf2f(fv.w);
        }
        __syncthreads();
#pragma unroll 8
        for (int k = 0; k < 64; k++) {
            float av[4], bv[4];
            *(float4*)av = *(const float4*)&Wsm[k][ty*4];
            *(float4*)bv = *(const float4*)&Fsm[k][tx*4];
#pragma unroll
            for (int i = 0; i < 4; i++)
#pragma unroll
                for (int j = 0; j < 4; j++) acc[i][j] += av[i]*bv[j];
        }
        if (tid < 64) {
            float s = 0.f;
            for (int k = 0; k < 64; k++) s += Wsm[k][tid];
            nsum += s;
        }
        __syncthreads();
    }
    int bh = b*8 + h;
#pragma unroll
    for (int i = 0; i < 4; i++) {
        int s = ty*4 + i;
#pragma unroll
        for (int j = 0; j < 4; j++) {
            int d = tx*4 + j;
            atomicAdd(&tok_acc[((size_t)bh*64 + s)*64 + d], acc[i][j]);
        }
    }
    if (tid < 64) atomicAdd(&norm_acc[bh*64 + tid], nsum);
}

// K3a: tok /= (norm + 1e-5)
__global__ void k_fintok(float* __restrict__ tok, const float* __restrict__ norm)
{
    int bh = blockIdx.x, tid = threadIdx.x;
    for (int idx = tid; idx < 4096; idx += 256) {
        int s = idx >> 6;
        tok[(size_t)bh*4096 + idx] /= (norm[bh*64 + s] + 1e-5f);
    }
}

// K3b: per b: kv = mean_h tok; kn = rownorm(kv@Wk^T); v = kv@Wv^T
__global__ __launch_bounds__(256) void k_kv(
    const float* __restrict__ tok, const float* __restrict__ Wk, const float* __restrict__ Wv,
    float* __restrict__ kn_out, float* __restrict__ v_out)
{
    __shared__ float KV[64][65];
    __shared__ float TMP[64][65];
    __shared__ float rn[64];
    int b = blockIdx.x, tid = threadIdx.x;
    for (int idx = tid; idx < 4096; idx += 256) {
        float s = 0.f;
        for (int h = 0; h < 8; ++h) s += tok[((size_t)(b*8 + h))*4096 + idx];
        KV[idx >> 6][idx & 63] = s * 0.125f;
    }
    __syncthreads();
    for (int idx = tid; idx < 4096; idx += 256) {
        int s = idx >> 6, d = idx & 63;
        float a = 0.f;
        for (int e = 0; e < 64; ++e) a += KV[s][e] * Wk[d*64 + e];
        TMP[s][d] = a;
    }
    __syncthreads();
    if (tid < 64) {
        float a = 0.f;
        for (int d = 0; d < 64; ++d) { float x = TMP[tid][d]; a += x*x; }
        rn[tid] = fmaxf(sqrtf(a), 1e-12f);
    }
    __syncthreads();
    for (int idx = tid; idx < 4096; idx += 256) {
        int s = idx >> 6, d = idx & 63;
        kn_out[(size_t)b*4096 + idx] = TMP[s][d] / rn[s];
    }
    for (int idx = tid; idx < 4096; idx += 256) {
        int s = idx >> 6, d = idx & 63;
        float a = 0.f;
        for (int e = 0; e < 64; ++e) a += KV[s][e] * Wv[d*64 + e];
        v_out[(size_t)b*4096 + idx] = a;
    }
}

// K3c: per (b,h): q = tok@Wq^T, cosine attn vs kn, softmax, @v, + srs*tok
__global__ __launch_bounds__(256) void k_attn(
    const float* __restrict__ tok, const float* __restrict__ Wq,
    const float* __restrict__ kn, const float* __restrict__ vbuf,
    const float* __restrict__ attn_scale, const float* __restrict__ srs,
    float* __restrict__ out_tok)
{
    __shared__ float Q[64][65];
    __shared__ float KN[64][65];
    __shared__ float L[64][65];
    __shared__ float rn[64];
    int h = blockIdx.x & 7, b = blockIdx.x >> 3;
    int bh = b*8 + h;
    int tid = threadIdx.x;
    for (int idx = tid; idx < 4096; idx += 256)
        KN[idx >> 6][idx & 63] = kn[(size_t)b*4096 + idx];
    __syncthreads();
    for (int idx = tid; idx < 4096; idx += 256) {
        int g = idx >> 6, d = idx & 63;
        float a = 0.f;
        for (int e = 0; e < 64; ++e) a += tok[(size_t)bh*4096 + g*64 + e] * Wq[d*64 + e];
        Q[g][d] = a;
    }
    __syncthreads();
    if (tid < 64) {
        float a = 0.f;
        for (int d = 0; d < 64; ++d) { float x = Q[tid][d]; a += x*x; }
        rn[tid] = fmaxf(sqrtf(a), 1e-12f);
    }
    __syncthreads();
    float scale = attn_scale[h];
    for (int idx = tid; idx < 4096; idx += 256) {
        int g = idx >> 6, s = idx & 63;
        float a = 0.f;
        for (int e = 0; e < 64; ++e) a += Q[g][e] * KN[s][e];
        L[g][s] = a / rn[g] * scale;
    }
    __syncthreads();
    if (tid < 64) {
        float mx = -1e30f;
        for (int s = 0; s < 64; ++s) mx = fmaxf(mx, L[tid][s]);
        float sm = 0.f;
        for (int s = 0; s < 64; ++s) { float e = expf(L[tid][s]-mx); L[tid][s] = e; sm += e; }
        float inv = 1.f/sm;
        for (int s = 0; s < 64; ++s) L[tid][s] *= inv;
    }
    __syncthreads();
    float srsv = srs[0];
    for (int idx = tid; idx < 4096; idx += 256) {
        int g = idx >> 6, d = idx & 63;
        float a = 0.f;
        for (int s = 0; s < 64; ++s) a += L[g][s] * vbuf[(size_t)b*4096 + s*64 + d];
        out_tok[(size_t)bh*4096 + idx] = a + srsv * tok[(size_t)bh*4096 + idx];
    }
}

// K3d: MTb[b][j][h*64+s] = sum_d out_tok[b,h,s,d] * Wout[j, h*64+d]  (bf16 out)
__global__ __launch_bounds__(256) void k_mt(
    const float* __restrict__ out_tok, const float* __restrict__ Wout,
    unsigned short* __restrict__ MTb)
{
    __shared__ float Wt[64][68];   // [d][j]
    __shared__ float Ot[64][68];   // [d][s]
    int jt = blockIdx.x, h = blockIdx.y, b = blockIdx.z;
    int j0 = jt * 64;
    int tid = threadIdx.x;
    int tx = tid & 15, ty = tid >> 4;
#pragma unroll
    for (int i = 0; i < 4; i++) {
        int flat = tid + i*256;
        int r = flat >> 4;
        int c4 = (flat & 15) * 4;
        float4 wv = *(const float4*)(Wout + (size_t)(j0+r)*512 + h*64 + c4);
        Wt[c4+0][r]=wv.x; Wt[c4+1][r]=wv.y; Wt[c4+2][r]=wv.z; Wt[c4+3][r]=wv.w;
        float4 ov = *(const float4*)(out_tok + ((size_t)(b*8+h)*64 + r)*64 + c4);
        Ot[c4+0][r]=ov.x; Ot[c4+1][r]=ov.y; Ot[c4+2][r]=ov.z; Ot[c4+3][r]=ov.w;
    }
    __syncthreads();
    float acc[4][4] = {{0.f}};
#pragma unroll 8
    for (int d = 0; d < 64; ++d) {
        float av[4], bv[4];
        *(float4*)av = *(const float4*)&Wt[d][ty*4];
        *(float4*)bv = *(const float4*)&Ot[d][tx*4];
#pragma unroll
        for (int i = 0; i < 4; i++)
#pragma unroll
            for (int j = 0; j < 4; j++) acc[i][j] += av[i]*bv[j];
    }
#pragma unroll
    for (int i = 0; i < 4; i++) {
        int j = j0 + ty*4 + i;
#pragma unroll
        for (int jj = 0; jj < 4; jj++) {
            int s = tx*4 + jj;
            MTb[((size_t)(b*256) + j)*512 + h*64 + s] = f2bf(acc[i][jj]);
        }
    }
}

// ---------------------------------------------------------------------------
// K5: MFMA GEMM. out[65536 x 256] = wbuf(bf16) @ MTb[b]^T + bout (fp32 out)
// ---------------------------------------------------------------------------
__global__ __launch_bounds__(256) void k_gemm2(
    const unsigned short* __restrict__ A, const unsigned short* __restrict__ Ball,
    const float* __restrict__ bias, float* __restrict__ C)
{
    __shared__ unsigned short As[128*32];
    __shared__ unsigned short Bs[128*32];
    int bid = blockIdx.x;             // 1024
    int rt = bid >> 1, ct = bid & 1;
    int m0 = rt*128, n0 = ct*128;
    const unsigned short* Bm = Ball + (size_t)(m0 >> 14) * 256 * 512;
    int tid = threadIdx.x;
    int lane = tid & 63, w = tid >> 6;
    int wr = w >> 1, wc = w & 1;
    int lr = lane & 15, lq = lane >> 4;

    f32x4 acc[4][4];
#pragma unroll
    for (int i = 0; i < 4; i++)
#pragma unroll
        for (int j = 0; j < 4; j++) acc[i][j] = (f32x4)(0.f);

    int r0 = tid >> 2, kq0 = (tid & 3) * 8;

    for (int k0 = 0; k0 < 512; k0 += 32) {
        __syncthreads();
        gl_lds16(A + (size_t)(m0 + r0)*512 + k0 + kq0,       &As[(size_t)tid*8]);
        gl_lds16(A + (size_t)(m0 + 64 + r0)*512 + k0 + kq0,  &As[(size_t)(tid+256)*8]);
        gl_lds16(Bm + (size_t)(n0 + r0)*512 + k0 + kq0,      &Bs[(size_t)tid*8]);
        gl_lds16(Bm + (size_t)(n0 + 64 + r0)*512 + k0 + kq0, &Bs[(size_t)(tid+256)*8]);
        __syncthreads();
        short8 af[4], bf[4];
#pragma unroll
        for (int i = 0; i < 4; i++) {
            af[i] = *(const short8*)&As[(wr*64 + i*16 + lr)*32 + lq*8];
            bf[i] = *(const short8*)&Bs[(wc*64 + i*16 + lr)*32 + lq*8];
        }
#pragma unroll
        for (int i = 0; i < 4; i++)
#pragma unroll
            for (int j = 0; j < 4; j++)
                acc[i][j] = __builtin_amdgcn_mfma_f32_16x16x32_bf16(af[i], bf[j], acc[i][j], 0, 0, 0);
    }

#pragma unroll
    for (int j = 0; j < 4; j++) {
        int n = n0 + wc*64 + j*16 + lr;
        float bv = bias[n];
#pragma unroll
        for (int i = 0; i < 4; i++) {
            int mrow = m0 + wr*64 + i*16 + lq*4;
#pragma unroll
            for (int r = 0; r < 4; r++)
                C[(size_t)(mrow + r)*256 + n] = acc[i][j][r] + bv;
        }
    }
}

// ---------------------------------------------------------------------------
extern "C" void kernel_launch(void* const* d_in, const int* in_sizes, int n_in,
                              void* d_out, int out_size, void* d_ws, size_t ws_size,
                              hipStream_t stream)
{
    const float* x      = (const float*)d_in[0];
    const float* Wx     = (const float*)d_in[1];
    const float* bx     = (const float*)d_in[2];
    const float* Wfx    = (const float*)d_in[3];
    const float* bfx    = (const float*)d_in[4];
    const float* Wslice = (const float*)d_in[5];
    const float* bslice = (const float*)d_in[6];
    const float* temperature = (const float*)d_in[7];
    const float* Wq     = (const float*)d_in[8];
    const float* Wk     = (const float*)d_in[9];
    const float* Wv     = (const float*)d_in[10];
    const float* attn_scale = (const float*)d_in[11];
    const float* srs    = (const float*)d_in[12];
    const float* Wout   = (const float*)d_in[13];
    const float* bout   = (const float*)d_in[14];
    float* out = (float*)d_out;
    float* ws  = (float*)d_ws;

    // workspace layout (float offsets) — total ~98.6 MiB
    float* tok  = ws + 0;          // 131072
    float* norm = ws + 131072;     // 2048
    float* bcat = ws + 133120;     // 1024
    float* kn   = ws + 134144;     // 16384
    float* vb   = ws + 150528;     // 16384
    float* ot   = ws + 166912;     // 131072
    unsigned short* Wcatb = (unsigned short*)(ws + 297984);  // 1024*256  -> 131072 floats
    unsigned short* MTb   = (unsigned short*)(ws + 429056);  // 4*256*512 -> 262144 floats
    unsigned short* xb    = (unsigned short*)(ws + 691200);  // 65536*256 -> 8388608 floats
    unsigned short* wbuf  = (unsigned short*)(ws + 9079808); // 65536*512 -> 16777216 floats
    unsigned short* fx    = (unsigned short*)d_out;          // 64 MiB scratch, consumed before k_gemm2

    hipMemsetAsync(tok, 0, 133120 * sizeof(float), stream);  // tok_acc + norm
    k_prep<<<1024, 64, 0, stream>>>(Wx, bx, Wfx, bfx, Wslice, bslice, Wcatb, bcat);
    k_xcast<<<8192, 256, 0, stream>>>(x, xb);
    k_gemm1<<<4096, 256, 0, stream>>>(xb, Wcatb, bcat, fx, wbuf);
    k_softmax<<<16384, 256, 0, stream>>>(wbuf, temperature);
    k_tok<<<dim3(16, 8, 4), 256, 0, stream>>>(wbuf, fx, tok, norm);
    k_fintok<<<32, 256, 0, stream>>>(tok, norm);
    k_kv<<<4, 256, 0, stream>>>(tok, Wk, Wv, kn, vb);
    k_attn<<<32, 256, 0, stream>>>(tok, Wq, kn, vb, attn_scale, srs, ot);
    k_mt<<<dim3(4, 8, 4), 256, 0, stream>>>(ot, Wout, MTb);
    k_gemm2<<<1024, 256, 0, stream>>>(wbuf, MTb, bout, out);
}

// Round 4
// 419.740 us; speedup vs baseline: 2.3465x; 1.3081x over previous
//
#include <hip/hip_runtime.h>
#include <math.h>

// Problem constants (Physics_Attention_Irregular_Mesh)
#define BQ   4
#define NTOK 16384
#define DIMM 256
#define HH   8
#define DDIM 64
#define SSL  64
#define INNERD 512
#define BN_TOK (BQ*NTOK)   // 65536

typedef __attribute__((ext_vector_type(8))) short short8;   // 8 bf16 (4 VGPRs)
typedef __attribute__((ext_vector_type(4))) float f32x4;    // 4 fp32 acc

// bf16 <-> f32 helpers (RNE)
__device__ inline float bf2f(unsigned short u) {
    union { float f; unsigned int i; } v; v.i = ((unsigned int)u) << 16; return v.f;
}
__device__ inline unsigned short f2bf(float f) {
    union { float f; unsigned int i; } v; v.f = f;
    unsigned int r = v.i + 0x7FFFu + ((v.i >> 16) & 1u);
    return (unsigned short)(r >> 16);
}

// async global->LDS, 16 B per lane (wave-uniform LDS base + lane*16)
__device__ __forceinline__ void gl_lds16(const void* g, void* l) {
    __builtin_amdgcn_global_load_lds(
        (const __attribute__((address_space(1))) unsigned int*)g,
        (__attribute__((address_space(3))) unsigned int*)l, 16, 0, 0);
}

// ---------------------------------------------------------------------------
// K0: merged weights (bf16 out).
//   Wcatb rows 0..511    = Wfx,                 bcat = bfx
//   Wcatb rows 512..1023 = Wslice @ Wx_h,       bcat = Wslice@bx_h + bslice
// ---------------------------------------------------------------------------
__global__ void k_prep(const float* __restrict__ Wx, const float* __restrict__ bx,
                       const float* __restrict__ Wfx, const float* __restrict__ bfx,
                       const float* __restrict__ Wslice, const float* __restrict__ bslice,
                       unsigned short* __restrict__ Wcatb, float* __restrict__ bcat)
{
    int row = blockIdx.x;   // 0..1023
    int t = threadIdx.x;    // 64
    if (row < 512) {
        for (int c = t; c < 256; c += 64) Wcatb[row*256 + c] = f2bf(Wfx[row*256 + c]);
        if (t == 0) bcat[row] = bfx[row];
    } else {
        int r = row - 512, h = r >> 6, s = r & 63;
        for (int c = t; c < 256; c += 64) {
            float acc = 0.f;
            for (int d = 0; d < 64; ++d)
                acc += Wslice[s*64 + d] * Wx[(h*64 + d)*256 + c];
            Wcatb[row*256 + c] = f2bf(acc);
        }
        if (t == 0) {
            float acc = bslice[s];
            for (int d = 0; d < 64; ++d) acc += Wslice[s*64 + d] * bx[h*64 + d];
            bcat[row] = acc;
        }
    }
}

// x (fp32) -> xb (bf16), 8 elems/thread
__global__ void k_xcast(const float* __restrict__ x, unsigned short* __restrict__ xb)
{
    size_t i = ((size_t)blockIdx.x*256 + threadIdx.x)*8;
    float4 a = *(const float4*)(x + i);
    float4 b = *(const float4*)(x + i + 4);
    *(ushort4*)(xb + i)     = make_ushort4(f2bf(a.x), f2bf(a.y), f2bf(a.z), f2bf(a.w));
    *(ushort4*)(xb + i + 4) = make_ushort4(f2bf(b.x), f2bf(b.y), f2bf(b.z), f2bf(b.w));
}

// ---------------------------------------------------------------------------
// K1: MFMA GEMM C[65536 x 1024] = xb @ Wcatb^T + bcat, with fused epilogues:
//   cols 0..511   -> fx_t[b,h,d,n] (bf16, transposed layout for k_tok)
//   cols 512..1023-> softmax over each head's 64 cols -> wbuf[token][h*64+s]
// 128x128 tile, 4 waves (2x2), each wave 4x4 frags 16x16x32, BK=32.
// ---------------------------------------------------------------------------
__global__ __launch_bounds__(256) void k_gemm1(
    const unsigned short* __restrict__ Xb, const unsigned short* __restrict__ Wb,
    const float* __restrict__ bias, const float* __restrict__ temperature,
    unsigned short* __restrict__ fx_t, unsigned short* __restrict__ wbuf)
{
    __shared__ unsigned short As[128*32];
    __shared__ unsigned short Bs[128*32];
    int bid = blockIdx.x;             // 4096
    int rt = bid >> 3, ct = bid & 7;  // consecutive blocks share rt (A-tile L2 reuse)
    int m0 = rt*128, n0 = ct*128;
    int tid = threadIdx.x;
    int lane = tid & 63, w = tid >> 6;
    int wr = w >> 1, wc = w & 1;
    int lr = lane & 15, lq = lane >> 4;

    f32x4 acc[4][4];
#pragma unroll
    for (int i = 0; i < 4; i++)
#pragma unroll
        for (int j = 0; j < 4; j++) acc[i][j] = (f32x4)(0.f);

    int r0 = tid >> 2, kq0 = (tid & 3) * 8;   // staging slot

    for (int k0 = 0; k0 < 256; k0 += 32) {
        __syncthreads();
        gl_lds16(Xb + (size_t)(m0 + r0)*256 + k0 + kq0,      &As[(size_t)tid*8]);
        gl_lds16(Xb + (size_t)(m0 + 64 + r0)*256 + k0 + kq0, &As[(size_t)(tid+256)*8]);
        gl_lds16(Wb + (size_t)(n0 + r0)*256 + k0 + kq0,      &Bs[(size_t)tid*8]);
        gl_lds16(Wb + (size_t)(n0 + 64 + r0)*256 + k0 + kq0, &Bs[(size_t)(tid+256)*8]);
        __syncthreads();
        short8 af[4], bf[4];
#pragma unroll
        for (int i = 0; i < 4; i++) {
            af[i] = *(const short8*)&As[(wr*64 + i*16 + lr)*32 + lq*8];
            bf[i] = *(const short8*)&Bs[(wc*64 + i*16 + lr)*32 + lq*8];
        }
#pragma unroll
        for (int i = 0; i < 4; i++)
#pragma unroll
            for (int j = 0; j < 4; j++)
                acc[i][j] = __builtin_amdgcn_mfma_f32_16x16x32_bf16(af[i], bf[j], acc[i][j], 0, 0, 0);
    }

    float bv[4];
#pragma unroll
    for (int j = 0; j < 4; j++) bv[j] = bias[n0 + wc*64 + j*16 + lr];

    if (n0 < 512) {
        // fx half: write transposed fx_t[(batch*8+h)*64+d][token]
        int h = (n0 + wc*64) >> 6;
        int batch = m0 >> 14;
#pragma unroll
        for (int i = 0; i < 4; i++) {
            int tokbase = m0 + wr*64 + i*16 + lq*4;
            int nloc = tokbase & (NTOK-1);
#pragma unroll
            for (int j = 0; j < 4; j++) {
                int d = j*16 + lr;
                ushort4 pk = make_ushort4(
                    f2bf(acc[i][j][0] + bv[j]), f2bf(acc[i][j][1] + bv[j]),
                    f2bf(acc[i][j][2] + bv[j]), f2bf(acc[i][j][3] + bv[j]));
                *(ushort4*)(fx_t + ((size_t)(batch*8 + h)*64 + d)*NTOK + nloc) = pk;
            }
        }
    } else {
        // logits half: per-row softmax over this head's 64 cols, write wbuf normal
        int h = (n0 - 512 + wc*64) >> 6;
        float it = 1.f / fmaxf(temperature[h], 1e-4f);
        int colbase = (n0 - 512) + wc*64;
#pragma unroll
        for (int i = 0; i < 4; i++) {
            int tokbase = m0 + wr*64 + i*16 + lq*4;
#pragma unroll
            for (int r = 0; r < 4; r++) {
                float v[4];
#pragma unroll
                for (int j = 0; j < 4; j++) v[j] = (acc[i][j][r] + bv[j]) * it;
                float mx = fmaxf(fmaxf(v[0], v[1]), fmaxf(v[2], v[3]));
                mx = fmaxf(mx, __shfl_xor(mx, 1));
                mx = fmaxf(mx, __shfl_xor(mx, 2));
                mx = fmaxf(mx, __shfl_xor(mx, 4));
                mx = fmaxf(mx, __shfl_xor(mx, 8));
                float e[4], sm = 0.f;
#pragma unroll
                for (int j = 0; j < 4; j++) { e[j] = __expf(v[j] - mx); sm += e[j]; }
                sm += __shfl_xor(sm, 1);
                sm += __shfl_xor(sm, 2);
                sm += __shfl_xor(sm, 4);
                sm += __shfl_xor(sm, 8);
                float inv = 1.f / sm;
                size_t rowoff = (size_t)(tokbase + r)*512 + colbase + lr;
#pragma unroll
                for (int j = 0; j < 4; j++)
                    wbuf[rowoff + j*16] = f2bf(e[j] * inv);
            }
        }
    }
}

// ---------------------------------------------------------------------------
// K2: MFMA tok-reduction. Per (b,h): C[64s x 64d] = sum_n w[n][s] fx[n][d].
// A (w) transposed in-LDS from wbuf[token][h*64+s]; B (fx_t) via gl_lds16.
// grid (32 chunks x 32 bh), 512 tokens per block, BK=32.
// ---------------------------------------------------------------------------
__global__ __launch_bounds__(256) void k_tok(
    const unsigned short* __restrict__ wbuf, const unsigned short* __restrict__ fx_t,
    float* __restrict__ tok_acc, float* __restrict__ norm_acc)
{
    __shared__ unsigned short As[64*32];   // [s][token] transposed w
    __shared__ unsigned short Bs[64*32];   // [d][token] fx_t rows
    __shared__ float nsm[256];
    int chunk = blockIdx.x;   // 0..31
    int bh = blockIdx.y;      // 0..31
    int b = bh >> 3, h = bh & 7;
    int n0 = chunk * 512;
    int tid = threadIdx.x;
    int lane = tid & 63, w = tid >> 6;
    int lr = lane & 15, lq = lane >> 4;

    f32x4 acc[4];
#pragma unroll
    for (int j = 0; j < 4; j++) acc[j] = (f32x4)(0.f);
    float nacc = 0.f;

    int sN = tid & 63, qN = tid >> 6;

    for (int kk = 0; kk < 512; kk += 32) {
        __syncthreads();
        // B tile: fx_t rows (d-major, token contiguous) -> one gl_lds16
        gl_lds16(fx_t + ((size_t)bh*64 + (tid>>2))*NTOK + n0 + kk + (tid&3)*8,
                 &Bs[(size_t)tid*8]);
        // A tile: transpose w[token][h*64+s] -> As[s][token]
        {
            int tk = tid >> 3;            // token-in-tile 0..31
            int s8 = (tid & 7) * 8;       // s base
            short8 g = *(const short8*)(wbuf +
                ((size_t)(b*NTOK + n0 + kk + tk))*512 + h*64 + s8);
#pragma unroll
            for (int j = 0; j < 8; j++)
                As[(s8 + j)*32 + tk] = ((unsigned short*)&g)[j];
        }
        __syncthreads();
        // norm partial: sum w over tokens (rows of As)
        {
            float ns = 0.f;
#pragma unroll
            for (int k = 0; k < 8; k++) ns += bf2f(As[sN*32 + qN*8 + k]);
            nacc += ns;
        }
        short8 af = *(const short8*)&As[(w*16 + lr)*32 + lq*8];
#pragma unroll
        for (int j = 0; j < 4; j++) {
            short8 bf = *(const short8*)&Bs[(j*16 + lr)*32 + lq*8];
            acc[j] = __builtin_amdgcn_mfma_f32_16x16x32_bf16(af, bf, acc[j], 0, 0, 0);
        }
    }

#pragma unroll
    for (int j = 0; j < 4; j++) {
        int d = j*16 + lr;
#pragma unroll
        for (int r = 0; r < 4; r++) {
            int s = w*16 + lq*4 + r;
            atomicAdd(&tok_acc[((size_t)bh*64 + s)*64 + d], acc[j][r]);
        }
    }
    __syncthreads();
    nsm[tid] = nacc;
    __syncthreads();
    if (tid < 64)
        atomicAdd(&norm_acc[bh*64 + tid],
                  nsm[tid] + nsm[tid+64] + nsm[tid+128] + nsm[tid+192]);
}

// K3a: tok /= (norm + 1e-5)
__global__ void k_fintok(float* __restrict__ tok, const float* __restrict__ norm)
{
    int bh = blockIdx.x, tid = threadIdx.x;
    for (int idx = tid; idx < 4096; idx += 256) {
        int s = idx >> 6;
        tok[(size_t)bh*4096 + idx] /= (norm[bh*64 + s] + 1e-5f);
    }
}

// K3b: per b: kv = mean_h tok; kn = rownorm(kv@Wk^T); v = kv@Wv^T
__global__ __launch_bounds__(256) void k_kv(
    const float* __restrict__ tok, const float* __restrict__ Wk, const float* __restrict__ Wv,
    float* __restrict__ kn_out, float* __restrict__ v_out)
{
    __shared__ float KV[64][65];
    __shared__ float TMP[64][65];
    __shared__ float rn[64];
    int b = blockIdx.x, tid = threadIdx.x;
    for (int idx = tid; idx < 4096; idx += 256) {
        float s = 0.f;
        for (int h = 0; h < 8; ++h) s += tok[((size_t)(b*8 + h))*4096 + idx];
        KV[idx >> 6][idx & 63] = s * 0.125f;
    }
    __syncthreads();
    for (int idx = tid; idx < 4096; idx += 256) {
        int s = idx >> 6, d = idx & 63;
        float a = 0.f;
        for (int e = 0; e < 64; ++e) a += KV[s][e] * Wk[d*64 + e];
        TMP[s][d] = a;
    }
    __syncthreads();
    if (tid < 64) {
        float a = 0.f;
        for (int d = 0; d < 64; ++d) { float x = TMP[tid][d]; a += x*x; }
        rn[tid] = fmaxf(sqrtf(a), 1e-12f);
    }
    __syncthreads();
    for (int idx = tid; idx < 4096; idx += 256) {
        int s = idx >> 6, d = idx & 63;
        kn_out[(size_t)b*4096 + idx] = TMP[s][d] / rn[s];
    }
    for (int idx = tid; idx < 4096; idx += 256) {
        int s = idx >> 6, d = idx & 63;
        float a = 0.f;
        for (int e = 0; e < 64; ++e) a += KV[s][e] * Wv[d*64 + e];
        v_out[(size_t)b*4096 + idx] = a;
    }
}

// K3c: per (b,h): q = tok@Wq^T, cosine attn vs kn, softmax, @v, + srs*tok
__global__ __launch_bounds__(256) void k_attn(
    const float* __restrict__ tok, const float* __restrict__ Wq,
    const float* __restrict__ kn, const float* __restrict__ vbuf,
    const float* __restrict__ attn_scale, const float* __restrict__ srs,
    float* __restrict__ out_tok)
{
    __shared__ float Q[64][65];
    __shared__ float KN[64][65];
    __shared__ float L[64][65];
    __shared__ float rn[64];
    int h = blockIdx.x & 7, b = blockIdx.x >> 3;
    int bh = b*8 + h;
    int tid = threadIdx.x;
    for (int idx = tid; idx < 4096; idx += 256)
        KN[idx >> 6][idx & 63] = kn[(size_t)b*4096 + idx];
    __syncthreads();
    for (int idx = tid; idx < 4096; idx += 256) {
        int g = idx >> 6, d = idx & 63;
        float a = 0.f;
        for (int e = 0; e < 64; ++e) a += tok[(size_t)bh*4096 + g*64 + e] * Wq[d*64 + e];
        Q[g][d] = a;
    }
    __syncthreads();
    if (tid < 64) {
        float a = 0.f;
        for (int d = 0; d < 64; ++d) { float x = Q[tid][d]; a += x*x; }
        rn[tid] = fmaxf(sqrtf(a), 1e-12f);
    }
    __syncthreads();
    float scale = attn_scale[h];
    for (int idx = tid; idx < 4096; idx += 256) {
        int g = idx >> 6, s = idx & 63;
        float a = 0.f;
        for (int e = 0; e < 64; ++e) a += Q[g][e] * KN[s][e];
        L[g][s] = a / rn[g] * scale;
    }
    __syncthreads();
    if (tid < 64) {
        float mx = -1e30f;
        for (int s = 0; s < 64; ++s) mx = fmaxf(mx, L[tid][s]);
        float sm = 0.f;
        for (int s = 0; s < 64; ++s) { float e = expf(L[tid][s]-mx); L[tid][s] = e; sm += e; }
        float inv = 1.f/sm;
        for (int s = 0; s < 64; ++s) L[tid][s] *= inv;
    }
    __syncthreads();
    float srsv = srs[0];
    for (int idx = tid; idx < 4096; idx += 256) {
        int g = idx >> 6, d = idx & 63;
        float a = 0.f;
        for (int s = 0; s < 64; ++s) a += L[g][s] * vbuf[(size_t)b*4096 + s*64 + d];
        out_tok[(size_t)bh*4096 + idx] = a + srsv * tok[(size_t)bh*4096 + idx];
    }
}

// K3d: MTb[b][j][h*64+s] = sum_d out_tok[b,h,s,d] * Wout[j, h*64+d]  (bf16 out)
__global__ __launch_bounds__(256) void k_mt(
    const float* __restrict__ out_tok, const float* __restrict__ Wout,
    unsigned short* __restrict__ MTb)
{
    __shared__ float Wt[64][68];   // [d][j]
    __shared__ float Ot[64][68];   // [d][s]
    int jt = blockIdx.x, h = blockIdx.y, b = blockIdx.z;
    int j0 = jt * 64;
    int tid = threadIdx.x;
    int tx = tid & 15, ty = tid >> 4;
#pragma unroll
    for (int i = 0; i < 4; i++) {
        int flat = tid + i*256;
        int r = flat >> 4;
        int c4 = (flat & 15) * 4;
        float4 wv = *(const float4*)(Wout + (size_t)(j0+r)*512 + h*64 + c4);
        Wt[c4+0][r]=wv.x; Wt[c4+1][r]=wv.y; Wt[c4+2][r]=wv.z; Wt[c4+3][r]=wv.w;
        float4 ov = *(const float4*)(out_tok + ((size_t)(b*8+h)*64 + r)*64 + c4);
        Ot[c4+0][r]=ov.x; Ot[c4+1][r]=ov.y; Ot[c4+2][r]=ov.z; Ot[c4+3][r]=ov.w;
    }
    __syncthreads();
    float acc[4][4] = {{0.f}};
#pragma unroll 8
    for (int d = 0; d < 64; ++d) {
        float av[4], bv[4];
        *(float4*)av = *(const float4*)&Wt[d][ty*4];
        *(float4*)bv = *(const float4*)&Ot[d][tx*4];
#pragma unroll
        for (int i = 0; i < 4; i++)
#pragma unroll
            for (int j = 0; j < 4; j++) acc[i][j] += av[i]*bv[j];
    }
#pragma unroll
    for (int i = 0; i < 4; i++) {
        int j = j0 + ty*4 + i;
#pragma unroll
        for (int jj = 0; jj < 4; jj++) {
            int s = tx*4 + jj;
            MTb[((size_t)(b*256) + j)*512 + h*64 + s] = f2bf(acc[i][jj]);
        }
    }
}

// ---------------------------------------------------------------------------
// K5: MFMA GEMM. out[65536 x 256] = wbuf(bf16) @ MTb[b]^T + bout (fp32 out)
// ---------------------------------------------------------------------------
__global__ __launch_bounds__(256) void k_gemm2(
    const unsigned short* __restrict__ A, const unsigned short* __restrict__ Ball,
    const float* __restrict__ bias, float* __restrict__ C)
{
    __shared__ unsigned short As[128*32];
    __shared__ unsigned short Bs[128*32];
    int bid = blockIdx.x;             // 1024
    int rt = bid >> 1, ct = bid & 1;
    int m0 = rt*128, n0 = ct*128;
    const unsigned short* Bm = Ball + (size_t)(m0 >> 14) * 256 * 512;
    int tid = threadIdx.x;
    int lane = tid & 63, w = tid >> 6;
    int wr = w >> 1, wc = w & 1;
    int lr = lane & 15, lq = lane >> 4;

    f32x4 acc[4][4];
#pragma unroll
    for (int i = 0; i < 4; i++)
#pragma unroll
        for (int j = 0; j < 4; j++) acc[i][j] = (f32x4)(0.f);

    int r0 = tid >> 2, kq0 = (tid & 3) * 8;

    for (int k0 = 0; k0 < 512; k0 += 32) {
        __syncthreads();
        gl_lds16(A + (size_t)(m0 + r0)*512 + k0 + kq0,       &As[(size_t)tid*8]);
        gl_lds16(A + (size_t)(m0 + 64 + r0)*512 + k0 + kq0,  &As[(size_t)(tid+256)*8]);
        gl_lds16(Bm + (size_t)(n0 + r0)*512 + k0 + kq0,      &Bs[(size_t)tid*8]);
        gl_lds16(Bm + (size_t)(n0 + 64 + r0)*512 + k0 + kq0, &Bs[(size_t)(tid+256)*8]);
        __syncthreads();
        short8 af[4], bf[4];
#pragma unroll
        for (int i = 0; i < 4; i++) {
            af[i] = *(const short8*)&As[(wr*64 + i*16 + lr)*32 + lq*8];
            bf[i] = *(const short8*)&Bs[(wc*64 + i*16 + lr)*32 + lq*8];
        }
#pragma unroll
        for (int i = 0; i < 4; i++)
#pragma unroll
            for (int j = 0; j < 4; j++)
                acc[i][j] = __builtin_amdgcn_mfma_f32_16x16x32_bf16(af[i], bf[j], acc[i][j], 0, 0, 0);
    }

#pragma unroll
    for (int j = 0; j < 4; j++) {
        int n = n0 + wc*64 + j*16 + lr;
        float bv = bias[n];
#pragma unroll
        for (int i = 0; i < 4; i++) {
            int mrow = m0 + wr*64 + i*16 + lq*4;
#pragma unroll
            for (int r = 0; r < 4; r++)
                C[(size_t)(mrow + r)*256 + n] = acc[i][j][r] + bv;
        }
    }
}

// ---------------------------------------------------------------------------
extern "C" void kernel_launch(void* const* d_in, const int* in_sizes, int n_in,
                              void* d_out, int out_size, void* d_ws, size_t ws_size,
                              hipStream_t stream)
{
    const float* x      = (const float*)d_in[0];
    const float* Wx     = (const float*)d_in[1];
    const float* bx     = (const float*)d_in[2];
    const float* Wfx    = (const float*)d_in[3];
    const float* bfx    = (const float*)d_in[4];
    const float* Wslice = (const float*)d_in[5];
    const float* bslice = (const float*)d_in[6];
    const float* temperature = (const float*)d_in[7];
    const float* Wq     = (const float*)d_in[8];
    const float* Wk     = (const float*)d_in[9];
    const float* Wv     = (const float*)d_in[10];
    const float* attn_scale = (const float*)d_in[11];
    const float* srs    = (const float*)d_in[12];
    const float* Wout   = (const float*)d_in[13];
    const float* bout   = (const float*)d_in[14];
    float* out = (float*)d_out;
    float* ws  = (float*)d_ws;

    // workspace layout (float offsets) — total ~99 MiB
    float* tok  = ws + 0;          // 131072
    float* norm = ws + 131072;     // 2048
    float* bcat = ws + 133120;     // 1024
    float* kn   = ws + 134144;     // 16384
    float* vb   = ws + 150528;     // 16384
    float* ot   = ws + 166912;     // 131072
    unsigned short* Wcatb = (unsigned short*)(ws + 297984);  // 1024*256  -> 131072 floats
    unsigned short* MTb   = (unsigned short*)(ws + 429056);  // 4*256*512 -> 262144 floats
    unsigned short* xb    = (unsigned short*)(ws + 691200);  // 65536*256 -> 8388608 floats
    unsigned short* wbuf  = (unsigned short*)(ws + 9079808); // 65536*512 -> 16777216 floats
    unsigned short* fx_t  = (unsigned short*)d_out;          // 64 MiB scratch, consumed by k_tok

    hipMemsetAsync(tok, 0, 133120 * sizeof(float), stream);  // tok_acc + norm
    k_prep<<<1024, 64, 0, stream>>>(Wx, bx, Wfx, bfx, Wslice, bslice, Wcatb, bcat);
    k_xcast<<<8192, 256, 0, stream>>>(x, xb);
    k_gemm1<<<4096, 256, 0, stream>>>(xb, Wcatb, bcat, temperature, fx_t, wbuf);
    k_tok<<<dim3(32, 32), 256, 0, stream>>>(wbuf, fx_t, tok, norm);
    k_fintok<<<32, 256, 0, stream>>>(tok, norm);
    k_kv<<<4, 256, 0, stream>>>(tok, Wk, Wv, kn, vb);
    k_attn<<<32, 256, 0, stream>>>(tok, Wq, kn, vb, attn_scale, srs, ot);
    k_mt<<<dim3(4, 8, 4), 256, 0, stream>>>(ot, Wout, MTb);
    k_gemm2<<<1024, 256, 0, stream>>>(wbuf, MTb, bout, out);
}

// Round 5
// 371.970 us; speedup vs baseline: 2.6478x; 1.1284x over previous
//
#include <hip/hip_runtime.h>
#include <math.h>

// Problem constants (Physics_Attention_Irregular_Mesh)
#define BQ   4
#define NTOK 16384
#define DIMM 256
#define HH   8
#define DDIM 64
#define SSL  64
#define INNERD 512
#define BN_TOK (BQ*NTOK)   // 65536

typedef __attribute__((ext_vector_type(8))) short short8;   // 8 bf16 (4 VGPRs)
typedef __attribute__((ext_vector_type(4))) float f32x4;    // 4 fp32 acc

// bf16 <-> f32 helpers (RNE)
__device__ inline float bf2f(unsigned short u) {
    union { float f; unsigned int i; } v; v.i = ((unsigned int)u) << 16; return v.f;
}
__device__ inline unsigned short f2bf(float f) {
    union { float f; unsigned int i; } v; v.f = f;
    unsigned int r = v.i + 0x7FFFu + ((v.i >> 16) & 1u);
    return (unsigned short)(r >> 16);
}

// async global->LDS, 16 B per lane (wave-uniform LDS base + lane*16)
__device__ __forceinline__ void gl_lds16(const void* g, void* l) {
    __builtin_amdgcn_global_load_lds(
        (const __attribute__((address_space(1))) unsigned int*)g,
        (__attribute__((address_space(3))) unsigned int*)l, 16, 0, 0);
}

// ---------------------------------------------------------------------------
// K0: merged weights (bf16 out).
// ---------------------------------------------------------------------------
__global__ void k_prep(const float* __restrict__ Wx, const float* __restrict__ bx,
                       const float* __restrict__ Wfx, const float* __restrict__ bfx,
                       const float* __restrict__ Wslice, const float* __restrict__ bslice,
                       unsigned short* __restrict__ Wcatb, float* __restrict__ bcat)
{
    int row = blockIdx.x;   // 0..1023
    int t = threadIdx.x;    // 64
    if (row < 512) {
        for (int c = t; c < 256; c += 64) Wcatb[row*256 + c] = f2bf(Wfx[row*256 + c]);
        if (t == 0) bcat[row] = bfx[row];
    } else {
        int r = row - 512, h = r >> 6, s = r & 63;
        for (int c = t; c < 256; c += 64) {
            float acc = 0.f;
            for (int d = 0; d < 64; ++d)
                acc += Wslice[s*64 + d] * Wx[(h*64 + d)*256 + c];
            Wcatb[row*256 + c] = f2bf(acc);
        }
        if (t == 0) {
            float acc = bslice[s];
            for (int d = 0; d < 64; ++d) acc += Wslice[s*64 + d] * bx[h*64 + d];
            bcat[row] = acc;
        }
    }
}

// x (fp32) -> xb (bf16), 8 elems/thread
__global__ void k_xcast(const float* __restrict__ x, unsigned short* __restrict__ xb)
{
    size_t i = ((size_t)blockIdx.x*256 + threadIdx.x)*8;
    float4 a = *(const float4*)(x + i);
    float4 b = *(const float4*)(x + i + 4);
    *(ushort4*)(xb + i)     = make_ushort4(f2bf(a.x), f2bf(a.y), f2bf(a.z), f2bf(a.w));
    *(ushort4*)(xb + i + 4) = make_ushort4(f2bf(b.x), f2bf(b.y), f2bf(b.z), f2bf(b.w));
}

// ---------------------------------------------------------------------------
// K1: MFMA GEMM C[65536 x 1024] = xb @ Wcatb^T + bcat, fused epilogues:
//   cols 0..511   -> fx_t[b,h,d,n] (bf16, transposed for k_tok)
//   cols 512..1023-> per-head softmax -> wbuf[token][h*64+s]
// XCD-aware swizzle: xcd = bid&7 owns 64 consecutive row-tiles; within an
// XCD temporally-adjacent blocks share the A row-tile (L2 reuse stays local).
// ---------------------------------------------------------------------------
__global__ __launch_bounds__(256) void k_gemm1(
    const unsigned short* __restrict__ Xb, const unsigned short* __restrict__ Wb,
    const float* __restrict__ bias, const float* __restrict__ temperature,
    unsigned short* __restrict__ fx_t, unsigned short* __restrict__ wbuf)
{
    __shared__ unsigned short As[128*32];
    __shared__ unsigned short Bs[128*32];
    int bid = blockIdx.x;             // 4096
    int xcd = bid & 7;
    int inner = bid >> 3;             // temporal order within one XCD
    int rt = xcd*64 + (inner >> 3);   // 0..511
    int ct = inner & 7;               // 0..7
    int m0 = rt*128, n0 = ct*128;
    int tid = threadIdx.x;
    int lane = tid & 63, w = tid >> 6;
    int wr = w >> 1, wc = w & 1;
    int lr = lane & 15, lq = lane >> 4;

    f32x4 acc[4][4];
#pragma unroll
    for (int i = 0; i < 4; i++)
#pragma unroll
        for (int j = 0; j < 4; j++) acc[i][j] = (f32x4)(0.f);

    int r0 = tid >> 2, kq0 = (tid & 3) * 8;   // staging slot

    for (int k0 = 0; k0 < 256; k0 += 32) {
        __syncthreads();
        gl_lds16(Xb + (size_t)(m0 + r0)*256 + k0 + kq0,      &As[(size_t)tid*8]);
        gl_lds16(Xb + (size_t)(m0 + 64 + r0)*256 + k0 + kq0, &As[(size_t)(tid+256)*8]);
        gl_lds16(Wb + (size_t)(n0 + r0)*256 + k0 + kq0,      &Bs[(size_t)tid*8]);
        gl_lds16(Wb + (size_t)(n0 + 64 + r0)*256 + k0 + kq0, &Bs[(size_t)(tid+256)*8]);
        __syncthreads();
        short8 af[4], bf[4];
#pragma unroll
        for (int i = 0; i < 4; i++) {
            af[i] = *(const short8*)&As[(wr*64 + i*16 + lr)*32 + lq*8];
            bf[i] = *(const short8*)&Bs[(wc*64 + i*16 + lr)*32 + lq*8];
        }
#pragma unroll
        for (int i = 0; i < 4; i++)
#pragma unroll
            for (int j = 0; j < 4; j++)
                acc[i][j] = __builtin_amdgcn_mfma_f32_16x16x32_bf16(af[i], bf[j], acc[i][j], 0, 0, 0);
    }

    float bv[4];
#pragma unroll
    for (int j = 0; j < 4; j++) bv[j] = bias[n0 + wc*64 + j*16 + lr];

    if (n0 < 512) {
        // fx half: write transposed fx_t[(batch*8+h)*64+d][token]
        int h = (n0 + wc*64) >> 6;
        int batch = m0 >> 14;
#pragma unroll
        for (int i = 0; i < 4; i++) {
            int tokbase = m0 + wr*64 + i*16 + lq*4;
            int nloc = tokbase & (NTOK-1);
#pragma unroll
            for (int j = 0; j < 4; j++) {
                int d = j*16 + lr;
                ushort4 pk = make_ushort4(
                    f2bf(acc[i][j][0] + bv[j]), f2bf(acc[i][j][1] + bv[j]),
                    f2bf(acc[i][j][2] + bv[j]), f2bf(acc[i][j][3] + bv[j]));
                *(ushort4*)(fx_t + ((size_t)(batch*8 + h)*64 + d)*NTOK + nloc) = pk;
            }
        }
    } else {
        // logits half: per-row softmax over this head's 64 cols
        int h = (n0 - 512 + wc*64) >> 6;
        float it = 1.f / fmaxf(temperature[h], 1e-4f);
        int colbase = (n0 - 512) + wc*64;
#pragma unroll
        for (int i = 0; i < 4; i++) {
            int tokbase = m0 + wr*64 + i*16 + lq*4;
#pragma unroll
            for (int r = 0; r < 4; r++) {
                float v[4];
#pragma unroll
                for (int j = 0; j < 4; j++) v[j] = (acc[i][j][r] + bv[j]) * it;
                float mx = fmaxf(fmaxf(v[0], v[1]), fmaxf(v[2], v[3]));
                mx = fmaxf(mx, __shfl_xor(mx, 1));
                mx = fmaxf(mx, __shfl_xor(mx, 2));
                mx = fmaxf(mx, __shfl_xor(mx, 4));
                mx = fmaxf(mx, __shfl_xor(mx, 8));
                float e[4], sm = 0.f;
#pragma unroll
                for (int j = 0; j < 4; j++) { e[j] = __expf(v[j] - mx); sm += e[j]; }
                sm += __shfl_xor(sm, 1);
                sm += __shfl_xor(sm, 2);
                sm += __shfl_xor(sm, 4);
                sm += __shfl_xor(sm, 8);
                float inv = 1.f / sm;
                size_t rowoff = (size_t)(tokbase + r)*512 + colbase + lr;
#pragma unroll
                for (int j = 0; j < 4; j++)
                    wbuf[rowoff + j*16] = f2bf(e[j] * inv);
            }
        }
    }
}

// ---------------------------------------------------------------------------
// K2: MFMA tok-reduction. Per (b,h): C[64s x 64d] = sum_n w[n][s] fx[n][d].
// ---------------------------------------------------------------------------
__global__ __launch_bounds__(256) void k_tok(
    const unsigned short* __restrict__ wbuf, const unsigned short* __restrict__ fx_t,
    float* __restrict__ tok_acc, float* __restrict__ norm_acc)
{
    __shared__ unsigned short As[64*32];   // [s][token] transposed w
    __shared__ unsigned short Bs[64*32];   // [d][token] fx_t rows
    __shared__ float nsm[256];
    int chunk = blockIdx.x;   // 0..31
    int bh = blockIdx.y;      // 0..31
    int b = bh >> 3, h = bh & 7;
    int n0 = chunk * 512;
    int tid = threadIdx.x;
    int lane = tid & 63, w = tid >> 6;
    int lr = lane & 15, lq = lane >> 4;

    f32x4 acc[4];
#pragma unroll
    for (int j = 0; j < 4; j++) acc[j] = (f32x4)(0.f);
    float nacc = 0.f;

    int sN = tid & 63, qN = tid >> 6;

    for (int kk = 0; kk < 512; kk += 32) {
        __syncthreads();
        gl_lds16(fx_t + ((size_t)bh*64 + (tid>>2))*NTOK + n0 + kk + (tid&3)*8,
                 &Bs[(size_t)tid*8]);
        {
            int tk = tid >> 3;            // token-in-tile 0..31
            int s8 = (tid & 7) * 8;       // s base
            short8 g = *(const short8*)(wbuf +
                ((size_t)(b*NTOK + n0 + kk + tk))*512 + h*64 + s8);
#pragma unroll
            for (int j = 0; j < 8; j++)
                As[(s8 + j)*32 + tk] = ((unsigned short*)&g)[j];
        }
        __syncthreads();
        {
            float ns = 0.f;
#pragma unroll
            for (int k = 0; k < 8; k++) ns += bf2f(As[sN*32 + qN*8 + k]);
            nacc += ns;
        }
        short8 af = *(const short8*)&As[(w*16 + lr)*32 + lq*8];
#pragma unroll
        for (int j = 0; j < 4; j++) {
            short8 bf = *(const short8*)&Bs[(j*16 + lr)*32 + lq*8];
            acc[j] = __builtin_amdgcn_mfma_f32_16x16x32_bf16(af, bf, acc[j], 0, 0, 0);
        }
    }

#pragma unroll
    for (int j = 0; j < 4; j++) {
        int d = j*16 + lr;
#pragma unroll
        for (int r = 0; r < 4; r++) {
            int s = w*16 + lq*4 + r;
            atomicAdd(&tok_acc[((size_t)bh*64 + s)*64 + d], acc[j][r]);
        }
    }
    __syncthreads();
    nsm[tid] = nacc;
    __syncthreads();
    if (tid < 64)
        atomicAdd(&norm_acc[bh*64 + tid],
                  nsm[tid] + nsm[tid+64] + nsm[tid+128] + nsm[tid+192]);
}

// K3b: per b: kv = mean_h (tok/(norm+1e-5)); kn = rownorm(kv@Wk^T); v = kv@Wv^T
__global__ __launch_bounds__(256) void k_kv(
    const float* __restrict__ tok, const float* __restrict__ norm,
    const float* __restrict__ Wk, const float* __restrict__ Wv,
    float* __restrict__ kn_out, float* __restrict__ v_out)
{
    __shared__ float KV[64][65];
    __shared__ float TMP[64][65];
    __shared__ float rn[64];
    __shared__ float inv[8][64];
    int b = blockIdx.x, tid = threadIdx.x;
    if (tid < 512 && tid >= 0) { /* 256 threads: 2 iters */ }
    for (int idx = tid; idx < 512; idx += 256) {
        int h = idx >> 6, s = idx & 63;
        inv[h][s] = 1.f / (norm[(b*8 + h)*64 + s] + 1e-5f);
    }
    __syncthreads();
    for (int idx = tid; idx < 4096; idx += 256) {
        int s = idx >> 6;
        float acc = 0.f;
        for (int h = 0; h < 8; ++h)
            acc += tok[((size_t)(b*8 + h))*4096 + idx] * inv[h][s];
        KV[s][idx & 63] = acc * 0.125f;
    }
    __syncthreads();
    for (int idx = tid; idx < 4096; idx += 256) {
        int s = idx >> 6, d = idx & 63;
        float a = 0.f;
        for (int e = 0; e < 64; ++e) a += KV[s][e] * Wk[d*64 + e];
        TMP[s][d] = a;
    }
    __syncthreads();
    if (tid < 64) {
        float a = 0.f;
        for (int d = 0; d < 64; ++d) { float x = TMP[tid][d]; a += x*x; }
        rn[tid] = fmaxf(sqrtf(a), 1e-12f);
    }
    __syncthreads();
    for (int idx = tid; idx < 4096; idx += 256) {
        int s = idx >> 6, d = idx & 63;
        kn_out[(size_t)b*4096 + idx] = TMP[s][d] / rn[s];
    }
    for (int idx = tid; idx < 4096; idx += 256) {
        int s = idx >> 6, d = idx & 63;
        float a = 0.f;
        for (int e = 0; e < 64; ++e) a += KV[s][e] * Wv[d*64 + e];
        v_out[(size_t)b*4096 + idx] = a;
    }
}

// K3c: per (b,h): tn = tok/(norm+1e-5); q = tn@Wq^T, cosine attn vs kn,
// softmax, @v, + srs*tn
__global__ __launch_bounds__(256) void k_attn(
    const float* __restrict__ tok, const float* __restrict__ norm,
    const float* __restrict__ Wq,
    const float* __restrict__ kn, const float* __restrict__ vbuf,
    const float* __restrict__ attn_scale, const float* __restrict__ srs,
    float* __restrict__ out_tok)
{
    __shared__ float TN[64][65];
    __shared__ float Q[64][65];
    __shared__ float KN[64][65];
    __shared__ float L[64][65];
    __shared__ float rn[64];
    int h = blockIdx.x & 7, b = blockIdx.x >> 3;
    int bh = b*8 + h;
    int tid = threadIdx.x;
    for (int idx = tid; idx < 4096; idx += 256) {
        int g = idx >> 6;
        TN[g][idx & 63] = tok[(size_t)bh*4096 + idx] / (norm[bh*64 + g] + 1e-5f);
        KN[g][idx & 63] = kn[(size_t)b*4096 + idx];
    }
    __syncthreads();
    for (int idx = tid; idx < 4096; idx += 256) {
        int g = idx >> 6, d = idx & 63;
        float a = 0.f;
        for (int e = 0; e < 64; ++e) a += TN[g][e] * Wq[d*64 + e];
        Q[g][d] = a;
    }
    __syncthreads();
    if (tid < 64) {
        float a = 0.f;
        for (int d = 0; d < 64; ++d) { float x = Q[tid][d]; a += x*x; }
        rn[tid] = fmaxf(sqrtf(a), 1e-12f);
    }
    __syncthreads();
    float scale = attn_scale[h];
    for (int idx = tid; idx < 4096; idx += 256) {
        int g = idx >> 6, s = idx & 63;
        float a = 0.f;
        for (int e = 0; e < 64; ++e) a += Q[g][e] * KN[s][e];
        L[g][s] = a / rn[g] * scale;
    }
    __syncthreads();
    if (tid < 64) {
        float mx = -1e30f;
        for (int s = 0; s < 64; ++s) mx = fmaxf(mx, L[tid][s]);
        float sm = 0.f;
        for (int s = 0; s < 64; ++s) { float e = expf(L[tid][s]-mx); L[tid][s] = e; sm += e; }
        float ivv = 1.f/sm;
        for (int s = 0; s < 64; ++s) L[tid][s] *= ivv;
    }
    __syncthreads();
    float srsv = srs[0];
    for (int idx = tid; idx < 4096; idx += 256) {
        int g = idx >> 6, d = idx & 63;
        float a = 0.f;
        for (int s = 0; s < 64; ++s) a += L[g][s] * vbuf[(size_t)b*4096 + s*64 + d];
        out_tok[(size_t)bh*4096 + idx] = a + srsv * TN[g][d];
    }
}

// K3d: MTb[b][j][h*64+s] = sum_d out_tok[b,h,s,d] * Wout[j, h*64+d]  (bf16 out)
__global__ __launch_bounds__(256) void k_mt(
    const float* __restrict__ out_tok, const float* __restrict__ Wout,
    unsigned short* __restrict__ MTb)
{
    __shared__ float Wt[64][68];   // [d][j]
    __shared__ float Ot[64][68];   // [d][s]
    int jt = blockIdx.x, h = blockIdx.y, b = blockIdx.z;
    int j0 = jt * 64;
    int tid = threadIdx.x;
    int tx = tid & 15, ty = tid >> 4;
#pragma unroll
    for (int i = 0; i < 4; i++) {
        int flat = tid + i*256;
        int r = flat >> 4;
        int c4 = (flat & 15) * 4;
        float4 wv = *(const float4*)(Wout + (size_t)(j0+r)*512 + h*64 + c4);
        Wt[c4+0][r]=wv.x; Wt[c4+1][r]=wv.y; Wt[c4+2][r]=wv.z; Wt[c4+3][r]=wv.w;
        float4 ov = *(const float4*)(out_tok + ((size_t)(b*8+h)*64 + r)*64 + c4);
        Ot[c4+0][r]=ov.x; Ot[c4+1][r]=ov.y; Ot[c4+2][r]=ov.z; Ot[c4+3][r]=ov.w;
    }
    __syncthreads();
    float acc[4][4] = {{0.f}};
#pragma unroll 8
    for (int d = 0; d < 64; ++d) {
        float av[4], bv[4];
        *(float4*)av = *(const float4*)&Wt[d][ty*4];
        *(float4*)bv = *(const float4*)&Ot[d][tx*4];
#pragma unroll
        for (int i = 0; i < 4; i++)
#pragma unroll
            for (int j = 0; j < 4; j++) acc[i][j] += av[i]*bv[j];
    }
#pragma unroll
    for (int i = 0; i < 4; i++) {
        int j = j0 + ty*4 + i;
#pragma unroll
        for (int jj = 0; jj < 4; jj++) {
            int s = tx*4 + jj;
            MTb[((size_t)(b*256) + j)*512 + h*64 + s] = f2bf(acc[i][jj]);
        }
    }
}

// ---------------------------------------------------------------------------
// K5: MFMA GEMM. out[65536 x 256] = wbuf(bf16) @ MTb[b]^T + bout (fp32 out)
// XCD-aware swizzle: same-rt blocks stay on one XCD.
// ---------------------------------------------------------------------------
__global__ __launch_bounds__(256) void k_gemm2(
    const unsigned short* __restrict__ A, const unsigned short* __restrict__ Ball,
    const float* __restrict__ bias, float* __restrict__ C)
{
    __shared__ unsigned short As[128*32];
    __shared__ unsigned short Bs[128*32];
    int bid = blockIdx.x;             // 1024
    int xcd = bid & 7;
    int inner = bid >> 3;             // 0..127
    int rt = xcd*64 + (inner >> 1);   // 0..511
    int ct = inner & 1;
    int m0 = rt*128, n0 = ct*128;
    const unsigned short* Bm = Ball + (size_t)(m0 >> 14) * 256 * 512;
    int tid = threadIdx.x;
    int lane = tid & 63, w = tid >> 6;
    int wr = w >> 1, wc = w & 1;
    int lr = lane & 15, lq = lane >> 4;

    f32x4 acc[4][4];
#pragma unroll
    for (int i = 0; i < 4; i++)
#pragma unroll
        for (int j = 0; j < 4; j++) acc[i][j] = (f32x4)(0.f);

    int r0 = tid >> 2, kq0 = (tid & 3) * 8;

    for (int k0 = 0; k0 < 512; k0 += 32) {
        __syncthreads();
        gl_lds16(A + (size_t)(m0 + r0)*512 + k0 + kq0,       &As[(size_t)tid*8]);
        gl_lds16(A + (size_t)(m0 + 64 + r0)*512 + k0 + kq0,  &As[(size_t)(tid+256)*8]);
        gl_lds16(Bm + (size_t)(n0 + r0)*512 + k0 + kq0,      &Bs[(size_t)tid*8]);
        gl_lds16(Bm + (size_t)(n0 + 64 + r0)*512 + k0 + kq0, &Bs[(size_t)(tid+256)*8]);
        __syncthreads();
        short8 af[4], bf[4];
#pragma unroll
        for (int i = 0; i < 4; i++) {
            af[i] = *(const short8*)&As[(wr*64 + i*16 + lr)*32 + lq*8];
            bf[i] = *(const short8*)&Bs[(wc*64 + i*16 + lr)*32 + lq*8];
        }
#pragma unroll
        for (int i = 0; i < 4; i++)
#pragma unroll
            for (int j = 0; j < 4; j++)
                acc[i][j] = __builtin_amdgcn_mfma_f32_16x16x32_bf16(af[i], bf[j], acc[i][j], 0, 0, 0);
    }

#pragma unroll
    for (int j = 0; j < 4; j++) {
        int n = n0 + wc*64 + j*16 + lr;
        float bv = bias[n];
#pragma unroll
        for (int i = 0; i < 4; i++) {
            int mrow = m0 + wr*64 + i*16 + lq*4;
#pragma unroll
            for (int r = 0; r < 4; r++)
                C[(size_t)(mrow + r)*256 + n] = acc[i][j][r] + bv;
        }
    }
}

// ---------------------------------------------------------------------------
extern "C" void kernel_launch(void* const* d_in, const int* in_sizes, int n_in,
                              void* d_out, int out_size, void* d_ws, size_t ws_size,
                              hipStream_t stream)
{
    const float* x      = (const float*)d_in[0];
    const float* Wx     = (const float*)d_in[1];
    const float* bx     = (const float*)d_in[2];
    const float* Wfx    = (const float*)d_in[3];
    const float* bfx    = (const float*)d_in[4];
    const float* Wslice = (const float*)d_in[5];
    const float* bslice = (const float*)d_in[6];
    const float* temperature = (const float*)d_in[7];
    const float* Wq     = (const float*)d_in[8];
    const float* Wk     = (const float*)d_in[9];
    const float* Wv     = (const float*)d_in[10];
    const float* attn_scale = (const float*)d_in[11];
    const float* srs    = (const float*)d_in[12];
    const float* Wout   = (const float*)d_in[13];
    const float* bout   = (const float*)d_in[14];
    float* out = (float*)d_out;
    float* ws  = (float*)d_ws;

    // workspace layout (float offsets) — total ~99 MiB
    float* tok  = ws + 0;          // 131072
    float* norm = ws + 131072;     // 2048
    float* bcat = ws + 133120;     // 1024
    float* kn   = ws + 134144;     // 16384
    float* vb   = ws + 150528;     // 16384
    float* ot   = ws + 166912;     // 131072
    unsigned short* Wcatb = (unsigned short*)(ws + 297984);  // 1024*256  -> 131072 floats
    unsigned short* MTb   = (unsigned short*)(ws + 429056);  // 4*256*512 -> 262144 floats
    unsigned short* xb    = (unsigned short*)(ws + 691200);  // 65536*256 -> 8388608 floats
    unsigned short* wbuf  = (unsigned short*)(ws + 9079808); // 65536*512 -> 16777216 floats
    unsigned short* fx_t  = (unsigned short*)d_out;          // 64 MiB scratch, consumed by k_tok

    hipMemsetAsync(tok, 0, 133120 * sizeof(float), stream);  // tok_acc + norm
    k_prep<<<1024, 64, 0, stream>>>(Wx, bx, Wfx, bfx, Wslice, bslice, Wcatb, bcat);
    k_xcast<<<8192, 256, 0, stream>>>(x, xb);
    k_gemm1<<<4096, 256, 0, stream>>>(xb, Wcatb, bcat, temperature, fx_t, wbuf);
    k_tok<<<dim3(32, 32), 256, 0, stream>>>(wbuf, fx_t, tok, norm);
    k_kv<<<4, 256, 0, stream>>>(tok, norm, Wk, Wv, kn, vb);
    k_attn<<<32, 256, 0, stream>>>(tok, norm, Wq, kn, vb, attn_scale, srs, ot);
    k_mt<<<dim3(4, 8, 4), 256, 0, stream>>>(ot, Wout, MTb);
    k_gemm2<<<1024, 256, 0, stream>>>(wbuf, MTb, bout, out);
}